// Round 12
// baseline (292.218 us; speedup 1.0000x reference)
//
#include <hip/hip_runtime.h>

#define N_NODES   100000
#define N_EDGES   1600000
#define EDGE_DIM  32
#define NODE_DIM  128
#define K1        192    // rec32 + send32 + node128 (glob folded into b1_eff)
#define HIDDEN    256
#define OUT_DIM   128
#define NCNT      (2 * N_NODES)
#define SCAN_BLK  1024
#define NSCAN     ((NCNT + SCAN_BLK - 1) / SCAN_BLK)   // 196

// ---- two-level counting-sort params ----
#define RSHIFT  10                    // 1024 nodes per range
#define NRANGES 98                    // ceil(100000/1024)
#define NBKT    (2 * NRANGES)         // 196 buckets, dir-major
#define SBLK    4096                  // edges per scatter block
#define NSBLK   ((N_EDGES + SBLK - 1) / SBLK)   // 391

typedef float  f32x4   __attribute__((ext_vector_type(4)));
typedef short  short8  __attribute__((ext_vector_type(8)));
typedef unsigned short ushort8 __attribute__((ext_vector_type(8)));
typedef unsigned short ushort4v __attribute__((ext_vector_type(4)));

// ---- BIG ws layout (4-byte words), ~142 MB ----
#define W_EBF    0                           // u32[1.6M*16] bf16 edge rows = 102.4 MB
#define W_BIN    25600000                    // u32[3.2M] packed (nl<<21|eid)
#define W_EIDS   28800000                    // int[3.2M]
#define W_FEATS  32000000                    // ushort[100000*64] = 3.2M words
#define W_W1T    35200000                    // ushort[256*192]
#define W_W2T    (W_W1T + 24576)             // ushort[128*256]
#define W_B1E    (W_W2T + 16384)             // float[256]
#define W_OFF    (W_B1E + 256)               // int[NCNT+1]
#define W_BCNT   (W_OFF + NCNT + 1)          // int[256]
#define W_BBASE  (W_BCNT + 256)              // int[256] (+sentinel)
#define W_BCUR   (W_BBASE + 256)             // int[256]
#define W_TOTAL  (W_BCUR + 256)

// ---- SMALL ws fallback layout (words), ~28.2 MB (eids path, proven r4/5) ----
#define S_FEATS_W  0
#define S_W1T_W    3200000
#define S_W2T_W    (S_W1T_W + 24576)
#define S_B1E_W    (S_W2T_W + 16384)
#define S_CNT_W    (S_B1E_W + 256)
#define S_OFF_W    (S_CNT_W + NCNT)
#define S_POS_W    (S_OFF_W + NCNT + 1)
#define S_EIDS_W   (S_POS_W + NCNT + 1)
#define S_BSUM_W   (S_EIDS_W + 2 * N_EDGES)

__device__ __forceinline__ unsigned short f2bf(float f) {
    unsigned int u = __float_as_uint(f);
    return (unsigned short)((u + 0x7fffu + ((u >> 16) & 1u)) >> 16);   // RNE
}

// ---------------------------------------------------------------------------
// Weight prep: W1T[n][k] (k<192), W2T[o][k], b1_eff = b1 + glob @ W1[192:224]
// ---------------------------------------------------------------------------
__global__ __launch_bounds__(256) void wcvt_kernel(
    const float* __restrict__ W1, const float* __restrict__ W2,
    const float* __restrict__ b1, const float* __restrict__ glob,
    unsigned short* __restrict__ W1T, unsigned short* __restrict__ W2T,
    float* __restrict__ b1e)
{
    int id = blockIdx.x * 256 + threadIdx.x;
    if (id < K1 * HIDDEN) {
        int n = id / K1, k = id - n * K1;
        W1T[id] = f2bf(W1[(size_t)k * HIDDEN + n]);
    } else if (id < K1 * HIDDEN + HIDDEN * OUT_DIM) {
        int id2 = id - K1 * HIDDEN;
        int o = id2 / HIDDEN, k = id2 - o * HIDDEN;
        W2T[id2] = f2bf(W2[(size_t)k * OUT_DIM + o]);
    } else if (id < K1 * HIDDEN + HIDDEN * OUT_DIM + HIDDEN) {
        int n = id - (K1 * HIDDEN + HIDDEN * OUT_DIM);
        float s = b1[n];
        #pragma unroll
        for (int j = 0; j < 32; ++j)
            s += glob[j] * W1[(size_t)(K1 + j) * HIDDEN + n];
        b1e[n] = s;
    }
}

// ---------------------------------------------------------------------------
// ecvt: streaming fp32 edge rows -> packed bf16 rows (205 MB -> 102.4 MB).
// Thread handles 8 floats: 32B read, 16B write, fully coalesced.
// ---------------------------------------------------------------------------
__global__ __launch_bounds__(256) void ecvt_kernel(
    const float* __restrict__ edge, unsigned int* __restrict__ ebf)
{
    int gid = blockIdx.x * 256 + threadIdx.x;       // 6.4M threads
    if (gid >= N_EDGES * (EDGE_DIM / 8)) return;
    const float4* p = (const float4*)&edge[(size_t)gid * 8];
    float4 v0 = p[0], v1 = p[1];
    uint4 o;
    o.x = (unsigned)f2bf(v0.x) | ((unsigned)f2bf(v0.y) << 16);
    o.y = (unsigned)f2bf(v0.z) | ((unsigned)f2bf(v0.w) << 16);
    o.z = (unsigned)f2bf(v1.x) | ((unsigned)f2bf(v1.y) << 16);
    o.w = (unsigned)f2bf(v1.z) | ((unsigned)f2bf(v1.w) << 16);
    *(uint4*)&ebf[(size_t)gid * 4] = o;
}

// ---------------------------------------------------------------------------
// bin_count: 196-bucket histogram, LDS-aggregated (r8 proven)
// ---------------------------------------------------------------------------
__global__ __launch_bounds__(512) void bin_count_kernel(
    const int* __restrict__ rcv, const int* __restrict__ snd,
    int* __restrict__ bcnt)
{
    __shared__ int h[NBKT];
    const int tid = threadIdx.x;
    for (int i = tid; i < NBKT; i += 512) h[i] = 0;
    __syncthreads();

    const int base = blockIdx.x * SBLK;
    #pragma unroll
    for (int k = 0; k < SBLK / 512; ++k) {
        int e = base + k * 512 + tid;
        if (e < N_EDGES) {
            atomicAdd(&h[rcv[e] >> RSHIFT], 1);
            atomicAdd(&h[NRANGES + (snd[e] >> RSHIFT)], 1);
        }
    }
    __syncthreads();
    for (int i = tid; i < NBKT; i += 512)
        if (h[i]) atomicAdd(&bcnt[i], h[i]);
}

// ---------------------------------------------------------------------------
// scan196: exclusive scan of bucket counts -> bbase (+sentinel), bcur copy;
// also writes the global CSR sentinel off[NCNT].
// ---------------------------------------------------------------------------
__global__ __launch_bounds__(256) void scan196_kernel(
    const int* __restrict__ bcnt, int* __restrict__ bbase, int* __restrict__ bcur,
    int* __restrict__ off)
{
    __shared__ int ts[256];
    const int t = threadIdx.x;
    int v = (t < NBKT) ? bcnt[t] : 0;
    ts[t] = v;
    __syncthreads();
    for (int d = 1; d < 256; d <<= 1) {
        int x = (t >= d) ? ts[t - d] : 0;
        __syncthreads();
        ts[t] += x;
        __syncthreads();
    }
    if (t < NBKT) { int ex = ts[t] - v; bbase[t] = ex; bcur[t] = ex; }
    if (t == 255) { bbase[NBKT] = ts[255]; off[NCNT] = 2 * N_EDGES; }
}

// ---------------------------------------------------------------------------
// bin_scatter_ids: block owns 4096 edges; packs (nl<<21)|eid and scatters
// into bucket-chunked regions (one global cursor claim per block-bucket).
// ---------------------------------------------------------------------------
__global__ __launch_bounds__(512) void bin_scatter_ids_kernel(
    const int* __restrict__ rcv, const int* __restrict__ snd,
    int*         __restrict__ bcur,
    unsigned int* __restrict__ bin)
{
    __shared__ int cntA[NBKT];
    __shared__ int baseS[NBKT];
    __shared__ int cntC[NBKT];

    const int tid  = threadIdx.x;
    const int base = blockIdx.x * SBLK;

    for (int i = tid; i < NBKT; i += 512) { cntA[i] = 0; cntC[i] = 0; }
    __syncthreads();

    int rk[SBLK / 512], sk[SBLK / 512];
    #pragma unroll
    for (int k = 0; k < SBLK / 512; ++k) {
        int e = base + k * 512 + tid;
        if (e < N_EDGES) {
            rk[k] = rcv[e]; sk[k] = snd[e];
            atomicAdd(&cntA[rk[k] >> RSHIFT], 1);
            atomicAdd(&cntA[NRANGES + (sk[k] >> RSHIFT)], 1);
        } else rk[k] = -1;
    }
    __syncthreads();

    for (int i = tid; i < NBKT; i += 512)
        baseS[i] = cntA[i] ? atomicAdd(&bcur[i], cntA[i]) : 0;
    __syncthreads();

    #pragma unroll
    for (int k = 0; k < SBLK / 512; ++k) {
        if (rk[k] < 0) continue;
        int e  = base + k * 512 + tid;
        int b0 = rk[k] >> RSHIFT;
        int b1 = NRANGES + (sk[k] >> RSHIFT);
        int s0 = baseS[b0] + atomicAdd(&cntC[b0], 1);
        int s1 = baseS[b1] + atomicAdd(&cntC[b1], 1);
        bin[s0] = ((unsigned)(rk[k] & ((1 << RSHIFT) - 1)) << 21) | (unsigned)e;
        bin[s1] = ((unsigned)(sk[k] & ((1 << RSHIFT) - 1)) << 21) | (unsigned)e;
    }
}

// ---------------------------------------------------------------------------
// bucket_fill: one block per bucket. LDS hist(1024) -> scan -> writes global
// CSR off[] AND scatters eids into the bucket's own L2-local span.
// ---------------------------------------------------------------------------
__global__ __launch_bounds__(1024) void bucket_fill_kernel(
    const unsigned int* __restrict__ bin,
    const int* __restrict__ bbase,
    int* __restrict__ off,
    int* __restrict__ eids)
{
    __shared__ int hist[1024];
    __shared__ int ts[1024];
    __shared__ int cur[1024];

    const int tid = threadIdx.x;
    const int b   = blockIdx.x;
    const int dir = (b >= NRANGES) ? 1 : 0;
    const int r   = dir ? (b - NRANGES) : b;
    const int lo  = r << RSHIFT;
    const int s0  = bbase[b], s1 = bbase[b + 1];

    hist[tid] = 0;
    __syncthreads();

    for (int i = s0 + tid; i < s1; i += 1024)
        atomicAdd(&hist[bin[i] >> 21], 1);
    __syncthreads();

    int v = hist[tid];
    ts[tid] = v;
    __syncthreads();
    for (int d = 1; d < 1024; d <<= 1) {
        int x = (tid >= d) ? ts[tid - d] : 0;
        __syncthreads();
        ts[tid] += x;
        __syncthreads();
    }
    int slot0 = s0 + ts[tid] - v;
    cur[tid] = slot0;

    const int rangeN = min(1024, N_NODES - lo);
    if (tid < rangeN) off[dir * N_NODES + lo + tid] = slot0;
    __syncthreads();

    for (int i = s0 + tid; i < s1; i += 1024) {
        unsigned int u = bin[i];
        int nl = u >> 21;
        int s = atomicAdd(&cur[nl], 1);
        eids[s] = (int)(u & 0x1FFFFFu);
    }
}

// ---------------------------------------------------------------------------
// gather_bf: 16 lanes per (node,dir) segment sum bf16 rows from the L3-hot
// 102.4 MB ebf buffer (random 64B rows, half the footprint of fp32).
// ---------------------------------------------------------------------------
__global__ __launch_bounds__(256) void gather_bf_kernel(
    const unsigned int* __restrict__ ebf,
    const int*   __restrict__ off,
    const int*   __restrict__ eids,
    unsigned short* __restrict__ feats_bf)
{
    int gid = blockIdx.x * 256 + threadIdx.x;
    int seg = gid >> 4;
    if (seg >= NCNT) return;
    const int l = gid & 15;

    int s = off[seg], e = off[seg + 1];
    float ax = 0.f, ay = 0.f;
    for (int i = s; i < e; ++i) {
        unsigned int u = ebf[(size_t)eids[i] * 16 + l];
        ax += __uint_as_float(u << 16);
        ay += __uint_as_float(u & 0xffff0000u);
    }
    int nodeI = (seg < N_NODES) ? seg : (seg - N_NODES);
    int cb    = (seg < N_NODES) ? 0 : 32;
    unsigned int pk = (unsigned)f2bf(ax) | ((unsigned)f2bf(ay) << 16);
    *(unsigned int*)&feats_bf[(size_t)nodeI * 64 + cb + l * 2] = pk;
}

// ---------------------------------------------------------------------------
// Small-ws fallback kernels (proven r4/5)
// ---------------------------------------------------------------------------
__global__ __launch_bounds__(256) void hist_kernel(
    const int* __restrict__ snd, const int* __restrict__ rcv, int* __restrict__ cnt)
{
    int e = blockIdx.x * 256 + threadIdx.x;
    if (e >= N_EDGES) return;
    atomicAdd(&cnt[rcv[e]], 1);
    atomicAdd(&cnt[N_NODES + snd[e]], 1);
}

__global__ __launch_bounds__(256) void scan1_kernel(
    const int* __restrict__ cnt, int* __restrict__ off, int* __restrict__ bsum)
{
    __shared__ int ts[256];
    const int t = threadIdx.x;
    const int base = blockIdx.x * SCAN_BLK + t * 4;
    int v[4], s = 0;
    #pragma unroll
    for (int j = 0; j < 4; ++j) {
        int idx = base + j;
        v[j] = (idx < NCNT) ? cnt[idx] : 0;
        s += v[j];
    }
    ts[t] = s;
    __syncthreads();
    for (int d = 1; d < 256; d <<= 1) {
        int x = (t >= d) ? ts[t - d] : 0;
        __syncthreads();
        ts[t] += x;
        __syncthreads();
    }
    int run = ts[t] - s;
    #pragma unroll
    for (int j = 0; j < 4; ++j) {
        int idx = base + j;
        if (idx < NCNT) off[idx] = run;
        run += v[j];
    }
    if (t == 255) bsum[blockIdx.x] = ts[255];
}

__global__ __launch_bounds__(256) void scan23_kernel(
    int* __restrict__ off, const int* __restrict__ bsum, int* __restrict__ pos)
{
    __shared__ int ts[256];
    __shared__ int sboff;
    const int t = threadIdx.x;
    int v = (t < NSCAN) ? bsum[t] : 0;
    ts[t] = v;
    __syncthreads();
    for (int d = 1; d < 256; d <<= 1) {
        int x = (t >= d) ? ts[t - d] : 0;
        __syncthreads();
        ts[t] += x;
        __syncthreads();
    }
    if (t == (int)blockIdx.x) sboff = ts[t] - v;
    __syncthreads();
    const int bo = sboff;
    const int base = blockIdx.x * SCAN_BLK + t * 4;
    #pragma unroll
    for (int j = 0; j < 4; ++j) {
        int idx = base + j;
        if (idx < NCNT) {
            int o = off[idx] + bo;
            off[idx] = o;
            pos[idx] = o;
        }
    }
    if (blockIdx.x == 0 && t == 0) off[NCNT] = 2 * N_EDGES;
}

__global__ __launch_bounds__(256) void fill_kernel(
    const int* __restrict__ snd, const int* __restrict__ rcv,
    int* __restrict__ pos, int* __restrict__ eids)
{
    int e = blockIdx.x * 256 + threadIdx.x;
    if (e >= N_EDGES) return;
    int p = atomicAdd(&pos[rcv[e]], 1);
    eids[p] = e;
    int q = atomicAdd(&pos[N_NODES + snd[e]], 1);
    eids[q] = e;
}

__global__ __launch_bounds__(256) void gather_kernel(
    const float* __restrict__ edge,
    const int*   __restrict__ off,
    const int*   __restrict__ eids,
    unsigned short* __restrict__ feats_bf)
{
    int seg = blockIdx.x * 32 + (threadIdx.x >> 3);
    if (seg >= NCNT) return;
    const int sub = threadIdx.x & 7;
    int s = off[seg], e = off[seg + 1];
    float4 a = make_float4(0.f, 0.f, 0.f, 0.f);
    for (int i = s; i < e; ++i) {
        int eid = eids[i];
        float4 v = *(const float4*)&edge[(size_t)eid * EDGE_DIM + sub * 4];
        a.x += v.x; a.y += v.y; a.z += v.z; a.w += v.w;
    }
    int nodeI = (seg < N_NODES) ? seg : (seg - N_NODES);
    int colB  = (seg < N_NODES) ? 0 : 32;
    ushort4v r;
    r.x = f2bf(a.x); r.y = f2bf(a.y); r.z = f2bf(a.z); r.w = f2bf(a.w);
    *(ushort4v*)&feats_bf[(size_t)nodeI * 64 + colB + sub * 4] = r;
}

// ---------------------------------------------------------------------------
// Fused GEMM1+GEMM2: 64 nodes/block, 512 threads (8 waves). Unchanged (r6).
// ---------------------------------------------------------------------------
__global__ __launch_bounds__(512) void gemm12_kernel(
    const unsigned short* __restrict__ feats_bf,
    const float* __restrict__ node,
    const unsigned short* __restrict__ W1T,
    const float* __restrict__ b1e,
    const unsigned short* __restrict__ W2T,
    const float* __restrict__ b2,
    float*       __restrict__ out)
{
    __shared__ unsigned short sA[64 * K1];       // 24 KB
    __shared__ unsigned short sH[64 * HIDDEN];   // 32 KB

    const int tid  = threadIdx.x;
    const int base = blockIdx.x * 64;

    for (int idx = tid; idx < 64 * 24; idx += 512) {
        int row = idx / 24;
        int c   = idx - row * 24;
        int g   = base + row; if (g >= N_NODES) g = N_NODES - 1;
        ushort8 r;
        if (c < 8) {
            r = *(const ushort8*)&feats_bf[(size_t)g * 64 + c * 8];
        } else {
            const float* np = &node[(size_t)g * NODE_DIM + (c - 8) * 8];
            float4 v0 = *(const float4*)np;
            float4 v1 = *(const float4*)(np + 4);
            r[0] = f2bf(v0.x); r[1] = f2bf(v0.y); r[2] = f2bf(v0.z); r[3] = f2bf(v0.w);
            r[4] = f2bf(v1.x); r[5] = f2bf(v1.y); r[6] = f2bf(v1.z); r[7] = f2bf(v1.w);
        }
        *(ushort8*)&sA[row * K1 + ((c ^ (row & 7)) << 3)] = r;
    }
    __syncthreads();

    const int wave = tid >> 6;
    const int lane = tid & 63;
    const int lm   = lane & 15;
    const int lk   = lane >> 4;

    short8 w1f[2][6];
    #pragma unroll
    for (int j = 0; j < 2; ++j) {
        int nt = 2 * wave + j;
        #pragma unroll
        for (int k = 0; k < 6; ++k)
            w1f[j][k] = *(const short8*)&W1T[(size_t)(nt * 16 + lm) * K1 + k * 32 + lk * 8];
    }

    f32x4 acc1[4][2];
    {
        float bv0 = b1e[(2 * wave) * 16 + lm];
        float bv1 = b1e[(2 * wave + 1) * 16 + lm];
        #pragma unroll
        for (int m = 0; m < 4; ++m) {
            acc1[m][0] = (f32x4){bv0, bv0, bv0, bv0};
            acc1[m][1] = (f32x4){bv1, bv1, bv1, bv1};
        }
    }

    #pragma unroll
    for (int k = 0; k < 6; ++k) {
        #pragma unroll
        for (int m = 0; m < 4; ++m) {
            int row   = m * 16 + lm;
            int chunk = k * 4 + lk;
            short8 af = *(const short8*)&sA[row * K1 + ((chunk ^ (row & 7)) << 3)];
            acc1[m][0] = __builtin_amdgcn_mfma_f32_16x16x32_bf16(af, w1f[0][k], acc1[m][0], 0, 0, 0);
            acc1[m][1] = __builtin_amdgcn_mfma_f32_16x16x32_bf16(af, w1f[1][k], acc1[m][1], 0, 0, 0);
        }
    }

    #pragma unroll
    for (int m = 0; m < 4; ++m) {
        #pragma unroll
        for (int j = 0; j < 2; ++j) {
            int col   = (2 * wave + j) * 16 + lm;
            int chunk = col >> 3;
            int cin   = col & 7;
            #pragma unroll
            for (int r = 0; r < 4; ++r) {
                int rowl = m * 16 + lk * 4 + r;
                float v = fmaxf(acc1[m][j][r], 0.0f);
                sH[rowl * HIDDEN + ((chunk ^ (rowl & 7)) << 3) + cin] = f2bf(v);
            }
        }
    }

    short8 w2f[8];
    #pragma unroll
    for (int k = 0; k < 8; ++k)
        w2f[k] = *(const short8*)&W2T[(size_t)(wave * 16 + lm) * HIDDEN + k * 32 + lk * 8];

    f32x4 acc2[4];
    {
        float bv = b2[wave * 16 + lm];
        #pragma unroll
        for (int m = 0; m < 4; ++m) acc2[m] = (f32x4){bv, bv, bv, bv};
    }
    __syncthreads();

    #pragma unroll
    for (int k = 0; k < 8; ++k) {
        #pragma unroll
        for (int m = 0; m < 4; ++m) {
            int row   = m * 16 + lm;
            int chunk = k * 4 + lk;
            short8 hf = *(const short8*)&sH[row * HIDDEN + ((chunk ^ (row & 7)) << 3)];
            acc2[m] = __builtin_amdgcn_mfma_f32_16x16x32_bf16(hf, w2f[k], acc2[m], 0, 0, 0);
        }
    }

    #pragma unroll
    for (int m = 0; m < 4; ++m) {
        #pragma unroll
        for (int r = 0; r < 4; ++r) {
            int grow = base + m * 16 + lk * 4 + r;
            if (grow < N_NODES)
                out[(size_t)grow * OUT_DIM + wave * 16 + lm] = acc2[m][r];
        }
    }
}

extern "C" void kernel_launch(void* const* d_in, const int* in_sizes, int n_in,
                              void* d_out, int out_size, void* d_ws, size_t ws_size,
                              hipStream_t stream) {
    const float* edge = (const float*)d_in[0];
    const int*   snd  = (const int*)  d_in[1];
    const int*   rcv  = (const int*)  d_in[2];
    const float* node = (const float*)d_in[3];
    const float* glob = (const float*)d_in[4];
    const float* W1   = (const float*)d_in[5];
    const float* b1   = (const float*)d_in[6];
    const float* W2   = (const float*)d_in[7];
    const float* b2   = (const float*)d_in[8];
    float* out = (float*)d_out;

    int* wsi = (int*)d_ws;
    const int wblocks = (K1 * HIDDEN + HIDDEN * OUT_DIM + HIDDEN + 255) / 256;

    if (ws_size >= (size_t)W_TOTAL * 4) {
        unsigned int*   ebf      = (unsigned int*)(wsi + W_EBF);
        unsigned int*   bin      = (unsigned int*)(wsi + W_BIN);
        int*            eids     = wsi + W_EIDS;
        unsigned short* feats_bf = (unsigned short*)(wsi + W_FEATS);
        unsigned short* W1T      = (unsigned short*)(wsi + W_W1T);
        unsigned short* W2T      = (unsigned short*)(wsi + W_W2T);
        float*          b1e      = (float*)(wsi + W_B1E);
        int* off   = wsi + W_OFF;
        int* bcnt  = wsi + W_BCNT;
        int* bbase = wsi + W_BBASE;
        int* bcur  = wsi + W_BCUR;

        hipMemsetAsync(bcnt, 0, NBKT * sizeof(int), stream);
        wcvt_kernel          <<<wblocks, 256, 0, stream>>>(W1, W2, b1, glob, W1T, W2T, b1e);
        bin_count_kernel     <<<NSBLK, 512, 0, stream>>>(rcv, snd, bcnt);
        ecvt_kernel          <<<(N_EDGES * 4 + 255) / 256, 256, 0, stream>>>(edge, ebf);
        scan196_kernel       <<<1, 256, 0, stream>>>(bcnt, bbase, bcur, off);
        bin_scatter_ids_kernel<<<NSBLK, 512, 0, stream>>>(rcv, snd, bcur, bin);
        bucket_fill_kernel   <<<NBKT, 1024, 0, stream>>>(bin, bbase, off, eids);
        gather_bf_kernel     <<<(NCNT * 16 + 255) / 256, 256, 0, stream>>>(ebf, off, eids, feats_bf);
        gemm12_kernel<<<(N_NODES + 63) / 64, 512, 0, stream>>>(
            feats_bf, node, W1T, b1e, W2T, b2, out);
    } else {
        unsigned short* feats_bf = (unsigned short*)(wsi + S_FEATS_W);
        unsigned short* W1T      = (unsigned short*)(wsi + S_W1T_W);
        unsigned short* W2T      = (unsigned short*)(wsi + S_W2T_W);
        float*          b1e      = (float*)(wsi + S_B1E_W);
        int* cnt  = wsi + S_CNT_W;
        int* off  = wsi + S_OFF_W;
        int* pos  = wsi + S_POS_W;
        int* eids = wsi + S_EIDS_W;
        int* bsum = wsi + S_BSUM_W;

        hipMemsetAsync(cnt, 0, NCNT * sizeof(int), stream);
        wcvt_kernel  <<<wblocks, 256, 0, stream>>>(W1, W2, b1, glob, W1T, W2T, b1e);
        const int eblocks = (N_EDGES + 255) / 256;
        hist_kernel  <<<eblocks, 256, 0, stream>>>(snd, rcv, cnt);
        scan1_kernel <<<NSCAN,   256, 0, stream>>>(cnt, off, bsum);
        scan23_kernel<<<NSCAN,   256, 0, stream>>>(off, bsum, pos);
        fill_kernel  <<<eblocks, 256, 0, stream>>>(snd, rcv, pos, eids);
        gather_kernel<<<(NCNT + 31) / 32, 256, 0, stream>>>(edge, off, eids, feats_bf);
        gemm12_kernel<<<(N_NODES + 63) / 64, 512, 0, stream>>>(
            feats_bf, node, W1T, b1e, W2T, b2, out);
    }
}

// Round 13
// 243.239 us; speedup vs baseline: 1.2014x; 1.2014x over previous
//
#include <hip/hip_runtime.h>

#define N_NODES   100000
#define N_EDGES   1600000
#define EDGE_DIM  32
#define NODE_DIM  128
#define K1        192    // rec32 + send32 + node128 (glob folded into b1_eff)
#define HIDDEN    256
#define OUT_DIM   128
#define NCNT      (2 * N_NODES)
#define SCAN_BLK  1024
#define NSCAN     ((NCNT + SCAN_BLK - 1) / SCAN_BLK)   // 196

// ---- two-level counting-sort params ----
#define RSHIFT  10                    // 1024 nodes per range
#define NRANGES 98                    // ceil(100000/1024)
#define NBKT    (2 * NRANGES)         // 196 buckets, dir-major
#define SBLK    4096                  // edges per scatter block
#define NSBLK   ((N_EDGES + SBLK - 1) / SBLK)   // 391

typedef float  f32x4   __attribute__((ext_vector_type(4)));
typedef short  short8  __attribute__((ext_vector_type(8)));
typedef unsigned short ushort8 __attribute__((ext_vector_type(8)));
typedef unsigned short ushort4v __attribute__((ext_vector_type(4)));

// ---- BIG ws layout (4-byte words), ~39.5 MB ----
#define W_BIN    0                           // u32[3.2M] packed (nl<<21|eid)
#define W_EIDS   3200000                     // int[3.2M]
#define W_FEATS  6400000                     // ushort[100000*64] = 3.2M words
#define W_W1T    9600000                     // ushort[256*192]
#define W_W2T    (W_W1T + 24576)             // ushort[128*256]
#define W_B1E    (W_W2T + 16384)             // float[256]
#define W_OFF    (W_B1E + 256)               // int[NCNT+1]
#define W_BCNT   (W_OFF + NCNT + 1)          // int[256]
#define W_BBASE  (W_BCNT + 256)              // int[256] (+sentinel)
#define W_BCUR   (W_BBASE + 256)             // int[256]
#define W_TOTAL  (W_BCUR + 256)

// ---- SMALL ws fallback layout (words), ~28.2 MB (eids path, proven r4/5) ----
#define S_FEATS_W  0
#define S_W1T_W    3200000
#define S_W2T_W    (S_W1T_W + 24576)
#define S_B1E_W    (S_W2T_W + 16384)
#define S_CNT_W    (S_B1E_W + 256)
#define S_OFF_W    (S_CNT_W + NCNT)
#define S_POS_W    (S_OFF_W + NCNT + 1)
#define S_EIDS_W   (S_POS_W + NCNT + 1)
#define S_BSUM_W   (S_EIDS_W + 2 * N_EDGES)

__device__ __forceinline__ unsigned short f2bf(float f) {
    unsigned int u = __float_as_uint(f);
    return (unsigned short)((u + 0x7fffu + ((u >> 16) & 1u)) >> 16);   // RNE
}

// ---------------------------------------------------------------------------
// Weight prep: W1T[n][k] (k<192), W2T[o][k], b1_eff = b1 + glob @ W1[192:224]
// ---------------------------------------------------------------------------
__global__ __launch_bounds__(256) void wcvt_kernel(
    const float* __restrict__ W1, const float* __restrict__ W2,
    const float* __restrict__ b1, const float* __restrict__ glob,
    unsigned short* __restrict__ W1T, unsigned short* __restrict__ W2T,
    float* __restrict__ b1e)
{
    int id = blockIdx.x * 256 + threadIdx.x;
    if (id < K1 * HIDDEN) {
        int n = id / K1, k = id - n * K1;
        W1T[id] = f2bf(W1[(size_t)k * HIDDEN + n]);
    } else if (id < K1 * HIDDEN + HIDDEN * OUT_DIM) {
        int id2 = id - K1 * HIDDEN;
        int o = id2 / HIDDEN, k = id2 - o * HIDDEN;
        W2T[id2] = f2bf(W2[(size_t)k * OUT_DIM + o]);
    } else if (id < K1 * HIDDEN + HIDDEN * OUT_DIM + HIDDEN) {
        int n = id - (K1 * HIDDEN + HIDDEN * OUT_DIM);
        float s = b1[n];
        #pragma unroll
        for (int j = 0; j < 32; ++j)
            s += glob[j] * W1[(size_t)(K1 + j) * HIDDEN + n];
        b1e[n] = s;
    }
}

// ---------------------------------------------------------------------------
// bin_count: 196-bucket histogram, LDS-aggregated
// ---------------------------------------------------------------------------
__global__ __launch_bounds__(512) void bin_count_kernel(
    const int* __restrict__ rcv, const int* __restrict__ snd,
    int* __restrict__ bcnt)
{
    __shared__ int h[NBKT];
    const int tid = threadIdx.x;
    for (int i = tid; i < NBKT; i += 512) h[i] = 0;
    __syncthreads();

    const int base = blockIdx.x * SBLK;
    #pragma unroll
    for (int k = 0; k < SBLK / 512; ++k) {
        int e = base + k * 512 + tid;
        if (e < N_EDGES) {
            atomicAdd(&h[rcv[e] >> RSHIFT], 1);
            atomicAdd(&h[NRANGES + (snd[e] >> RSHIFT)], 1);
        }
    }
    __syncthreads();
    for (int i = tid; i < NBKT; i += 512)
        if (h[i]) atomicAdd(&bcnt[i], h[i]);
}

// ---------------------------------------------------------------------------
// scan196: exclusive scan of bucket counts -> bbase (+sentinel), bcur copy;
// also writes the global CSR sentinel off[NCNT].
// ---------------------------------------------------------------------------
__global__ __launch_bounds__(256) void scan196_kernel(
    const int* __restrict__ bcnt, int* __restrict__ bbase, int* __restrict__ bcur,
    int* __restrict__ off)
{
    __shared__ int ts[256];
    const int t = threadIdx.x;
    int v = (t < NBKT) ? bcnt[t] : 0;
    ts[t] = v;
    __syncthreads();
    for (int d = 1; d < 256; d <<= 1) {
        int x = (t >= d) ? ts[t - d] : 0;
        __syncthreads();
        ts[t] += x;
        __syncthreads();
    }
    if (t < NBKT) { int ex = ts[t] - v; bbase[t] = ex; bcur[t] = ex; }
    if (t == 255) { bbase[NBKT] = ts[255]; off[NCNT] = 2 * N_EDGES; }
}

// ---------------------------------------------------------------------------
// bin_scatter_ids: block owns 4096 edges; packs (nl<<21)|eid and scatters
// into bucket-chunked regions (one global cursor claim per block-bucket).
// ---------------------------------------------------------------------------
__global__ __launch_bounds__(512) void bin_scatter_ids_kernel(
    const int* __restrict__ rcv, const int* __restrict__ snd,
    int*         __restrict__ bcur,
    unsigned int* __restrict__ bin)
{
    __shared__ int cntA[NBKT];
    __shared__ int baseS[NBKT];
    __shared__ int cntC[NBKT];

    const int tid  = threadIdx.x;
    const int base = blockIdx.x * SBLK;

    for (int i = tid; i < NBKT; i += 512) { cntA[i] = 0; cntC[i] = 0; }
    __syncthreads();

    int rk[SBLK / 512], sk[SBLK / 512];
    #pragma unroll
    for (int k = 0; k < SBLK / 512; ++k) {
        int e = base + k * 512 + tid;
        if (e < N_EDGES) {
            rk[k] = rcv[e]; sk[k] = snd[e];
            atomicAdd(&cntA[rk[k] >> RSHIFT], 1);
            atomicAdd(&cntA[NRANGES + (sk[k] >> RSHIFT)], 1);
        } else rk[k] = -1;
    }
    __syncthreads();

    for (int i = tid; i < NBKT; i += 512)
        baseS[i] = cntA[i] ? atomicAdd(&bcur[i], cntA[i]) : 0;
    __syncthreads();

    #pragma unroll
    for (int k = 0; k < SBLK / 512; ++k) {
        if (rk[k] < 0) continue;
        int e  = base + k * 512 + tid;
        int b0 = rk[k] >> RSHIFT;
        int b1 = NRANGES + (sk[k] >> RSHIFT);
        int s0 = baseS[b0] + atomicAdd(&cntC[b0], 1);
        int s1 = baseS[b1] + atomicAdd(&cntC[b1], 1);
        bin[s0] = ((unsigned)(rk[k] & ((1 << RSHIFT) - 1)) << 21) | (unsigned)e;
        bin[s1] = ((unsigned)(sk[k] & ((1 << RSHIFT) - 1)) << 21) | (unsigned)e;
    }
}

// ---------------------------------------------------------------------------
// bucket_fill: one block per bucket. LDS hist(1024) -> scan -> writes global
// CSR off[] AND scatters eids into the bucket's own L2-local span.
// ---------------------------------------------------------------------------
__global__ __launch_bounds__(1024) void bucket_fill_kernel(
    const unsigned int* __restrict__ bin,
    const int* __restrict__ bbase,
    int* __restrict__ off,
    int* __restrict__ eids)
{
    __shared__ int hist[1024];
    __shared__ int ts[1024];
    __shared__ int cur[1024];

    const int tid = threadIdx.x;
    const int b   = blockIdx.x;
    const int dir = (b >= NRANGES) ? 1 : 0;
    const int r   = dir ? (b - NRANGES) : b;
    const int lo  = r << RSHIFT;
    const int s0  = bbase[b], s1 = bbase[b + 1];

    hist[tid] = 0;
    __syncthreads();

    for (int i = s0 + tid; i < s1; i += 1024)
        atomicAdd(&hist[bin[i] >> 21], 1);
    __syncthreads();

    int v = hist[tid];
    ts[tid] = v;
    __syncthreads();
    for (int d = 1; d < 1024; d <<= 1) {
        int x = (tid >= d) ? ts[tid - d] : 0;
        __syncthreads();
        ts[tid] += x;
        __syncthreads();
    }
    int slot0 = s0 + ts[tid] - v;
    cur[tid] = slot0;

    const int rangeN = min(1024, N_NODES - lo);
    if (tid < rangeN) off[dir * N_NODES + lo + tid] = slot0;
    __syncthreads();

    for (int i = s0 + tid; i < s1; i += 1024) {
        unsigned int u = bin[i];
        int nl = u >> 21;
        int s = atomicAdd(&cur[nl], 1);
        eids[s] = (int)(u & 0x1FFFFFu);
    }
}

// ---------------------------------------------------------------------------
// gather: 8 lanes per (node,dir) segment sum fp32 edge rows via eids.
// Unrolled x2 for more outstanding misses (line-miss-rate bound).
// ---------------------------------------------------------------------------
__global__ __launch_bounds__(256) void gather_kernel(
    const float* __restrict__ edge,
    const int*   __restrict__ off,
    const int*   __restrict__ eids,
    unsigned short* __restrict__ feats_bf)
{
    int seg = blockIdx.x * 32 + (threadIdx.x >> 3);
    if (seg >= NCNT) return;
    const int sub = threadIdx.x & 7;
    int s = off[seg], e = off[seg + 1];

    float4 a  = make_float4(0.f, 0.f, 0.f, 0.f);
    float4 a2 = make_float4(0.f, 0.f, 0.f, 0.f);
    int i = s;
    for (; i + 2 <= e; i += 2) {
        int e0 = eids[i], e1 = eids[i + 1];
        float4 v0 = *(const float4*)&edge[(size_t)e0 * EDGE_DIM + sub * 4];
        float4 v1 = *(const float4*)&edge[(size_t)e1 * EDGE_DIM + sub * 4];
        a.x  += v0.x; a.y  += v0.y; a.z  += v0.z; a.w  += v0.w;
        a2.x += v1.x; a2.y += v1.y; a2.z += v1.z; a2.w += v1.w;
    }
    if (i < e) {
        float4 v = *(const float4*)&edge[(size_t)eids[i] * EDGE_DIM + sub * 4];
        a.x += v.x; a.y += v.y; a.z += v.z; a.w += v.w;
    }
    a.x += a2.x; a.y += a2.y; a.z += a2.z; a.w += a2.w;

    int nodeI = (seg < N_NODES) ? seg : (seg - N_NODES);
    int colB  = (seg < N_NODES) ? 0 : 32;
    ushort4v r;
    r.x = f2bf(a.x); r.y = f2bf(a.y); r.z = f2bf(a.z); r.w = f2bf(a.w);
    *(ushort4v*)&feats_bf[(size_t)nodeI * 64 + colB + sub * 4] = r;
}

// ---------------------------------------------------------------------------
// Small-ws fallback kernels (proven r4/5)
// ---------------------------------------------------------------------------
__global__ __launch_bounds__(256) void hist_kernel(
    const int* __restrict__ snd, const int* __restrict__ rcv, int* __restrict__ cnt)
{
    int e = blockIdx.x * 256 + threadIdx.x;
    if (e >= N_EDGES) return;
    atomicAdd(&cnt[rcv[e]], 1);
    atomicAdd(&cnt[N_NODES + snd[e]], 1);
}

__global__ __launch_bounds__(256) void scan1_kernel(
    const int* __restrict__ cnt, int* __restrict__ off, int* __restrict__ bsum)
{
    __shared__ int ts[256];
    const int t = threadIdx.x;
    const int base = blockIdx.x * SCAN_BLK + t * 4;
    int v[4], s = 0;
    #pragma unroll
    for (int j = 0; j < 4; ++j) {
        int idx = base + j;
        v[j] = (idx < NCNT) ? cnt[idx] : 0;
        s += v[j];
    }
    ts[t] = s;
    __syncthreads();
    for (int d = 1; d < 256; d <<= 1) {
        int x = (t >= d) ? ts[t - d] : 0;
        __syncthreads();
        ts[t] += x;
        __syncthreads();
    }
    int run = ts[t] - s;
    #pragma unroll
    for (int j = 0; j < 4; ++j) {
        int idx = base + j;
        if (idx < NCNT) off[idx] = run;
        run += v[j];
    }
    if (t == 255) bsum[blockIdx.x] = ts[255];
}

__global__ __launch_bounds__(256) void scan23_kernel(
    int* __restrict__ off, const int* __restrict__ bsum, int* __restrict__ pos)
{
    __shared__ int ts[256];
    __shared__ int sboff;
    const int t = threadIdx.x;
    int v = (t < NSCAN) ? bsum[t] : 0;
    ts[t] = v;
    __syncthreads();
    for (int d = 1; d < 256; d <<= 1) {
        int x = (t >= d) ? ts[t - d] : 0;
        __syncthreads();
        ts[t] += x;
        __syncthreads();
    }
    if (t == (int)blockIdx.x) sboff = ts[t] - v;
    __syncthreads();
    const int bo = sboff;
    const int base = blockIdx.x * SCAN_BLK + t * 4;
    #pragma unroll
    for (int j = 0; j < 4; ++j) {
        int idx = base + j;
        if (idx < NCNT) {
            int o = off[idx] + bo;
            off[idx] = o;
            pos[idx] = o;
        }
    }
    if (blockIdx.x == 0 && t == 0) off[NCNT] = 2 * N_EDGES;
}

__global__ __launch_bounds__(256) void fill_kernel(
    const int* __restrict__ snd, const int* __restrict__ rcv,
    int* __restrict__ pos, int* __restrict__ eids)
{
    int e = blockIdx.x * 256 + threadIdx.x;
    if (e >= N_EDGES) return;
    int p = atomicAdd(&pos[rcv[e]], 1);
    eids[p] = e;
    int q = atomicAdd(&pos[N_NODES + snd[e]], 1);
    eids[q] = e;
}

// ---------------------------------------------------------------------------
// Fused GEMM1+GEMM2: 64 nodes/block, 512 threads (8 waves).
// NEW wave mapping: wave = (row-half mh, n-quarter nq). Each ds_read_b128 of
// an A/h fragment feeds 4 (GEMM1) / 2 (GEMM2) MFMAs; block LDS reads halve
// (448 -> 224 b128). W1/W2 frags loaded per-k from L2-hot W-T (VGPR cap 128
// via __launch_bounds__(512,4) keeps 2 blocks/CU resident).
// ---------------------------------------------------------------------------
__global__ __launch_bounds__(512, 4) void gemm12_kernel(
    const unsigned short* __restrict__ feats_bf,
    const float* __restrict__ node,
    const unsigned short* __restrict__ W1T,
    const float* __restrict__ b1e,
    const unsigned short* __restrict__ W2T,
    const float* __restrict__ b2,
    float*       __restrict__ out)
{
    __shared__ unsigned short sA[64 * K1];       // 24 KB
    __shared__ unsigned short sH[64 * HIDDEN];   // 32 KB

    const int tid  = threadIdx.x;
    const int base = blockIdx.x * 64;

    for (int idx = tid; idx < 64 * 24; idx += 512) {
        int row = idx / 24;
        int c   = idx - row * 24;
        int g   = base + row; if (g >= N_NODES) g = N_NODES - 1;
        ushort8 r;
        if (c < 8) {
            r = *(const ushort8*)&feats_bf[(size_t)g * 64 + c * 8];
        } else {
            const float* np = &node[(size_t)g * NODE_DIM + (c - 8) * 8];
            float4 v0 = *(const float4*)np;
            float4 v1 = *(const float4*)(np + 4);
            r[0] = f2bf(v0.x); r[1] = f2bf(v0.y); r[2] = f2bf(v0.z); r[3] = f2bf(v0.w);
            r[4] = f2bf(v1.x); r[5] = f2bf(v1.y); r[6] = f2bf(v1.z); r[7] = f2bf(v1.w);
        }
        *(ushort8*)&sA[row * K1 + ((c ^ (row & 7)) << 3)] = r;
    }
    __syncthreads();

    const int wave = tid >> 6;
    const int lane = tid & 63;
    const int lm   = lane & 15;
    const int lk   = lane >> 4;
    const int mh   = wave >> 2;    // row-half: rows mh*32 .. mh*32+31
    const int nq   = wave & 3;     // n-quarter

    // ---- GEMM1: n-tiles nq*4..nq*4+3, m-tiles mh*2..mh*2+1, K=192 ----
    f32x4 acc1[2][4];
    #pragma unroll
    for (int j = 0; j < 4; ++j) {
        float bv = b1e[(nq * 4 + j) * 16 + lm];
        acc1[0][j] = (f32x4){bv, bv, bv, bv};
        acc1[1][j] = (f32x4){bv, bv, bv, bv};
    }

    #pragma unroll
    for (int k = 0; k < 6; ++k) {
        short8 w1f[4];
        #pragma unroll
        for (int j = 0; j < 4; ++j)
            w1f[j] = *(const short8*)&W1T[(size_t)((nq * 4 + j) * 16 + lm) * K1 + k * 32 + lk * 8];
        #pragma unroll
        for (int m = 0; m < 2; ++m) {
            int row   = (mh * 2 + m) * 16 + lm;
            int chunk = k * 4 + lk;
            short8 af = *(const short8*)&sA[row * K1 + ((chunk ^ (row & 7)) << 3)];
            #pragma unroll
            for (int j = 0; j < 4; ++j)
                acc1[m][j] = __builtin_amdgcn_mfma_f32_16x16x32_bf16(af, w1f[j], acc1[m][j], 0, 0, 0);
        }
    }

    // ---- relu -> sH (bf16, swizzled). C layout: col=lm, row=lk*4+r ----
    #pragma unroll
    for (int m = 0; m < 2; ++m) {
        #pragma unroll
        for (int j = 0; j < 4; ++j) {
            int col   = (nq * 4 + j) * 16 + lm;
            int chunk = col >> 3;
            int cin   = col & 7;
            #pragma unroll
            for (int r = 0; r < 4; ++r) {
                int rowl = (mh * 2 + m) * 16 + lk * 4 + r;
                float v = fmaxf(acc1[m][j][r], 0.0f);
                sH[rowl * HIDDEN + ((chunk ^ (rowl & 7)) << 3) + cin] = f2bf(v);
            }
        }
    }

    // ---- W2 fragments preloaded before barrier (overlap with convergence) ----
    short8 w2f[8][2];
    #pragma unroll
    for (int k = 0; k < 8; ++k)
        #pragma unroll
        for (int j2 = 0; j2 < 2; ++j2)
            w2f[k][j2] = *(const short8*)&W2T[(size_t)((nq * 2 + j2) * 16 + lm) * HIDDEN + k * 32 + lk * 8];

    f32x4 acc2[2][2];
    #pragma unroll
    for (int j2 = 0; j2 < 2; ++j2) {
        float bv = b2[(nq * 2 + j2) * 16 + lm];
        acc2[0][j2] = (f32x4){bv, bv, bv, bv};
        acc2[1][j2] = (f32x4){bv, bv, bv, bv};
    }
    __syncthreads();

    // ---- GEMM2: n-tiles nq*2..nq*2+1, m-tiles mh*2..mh*2+1, K=256 ----
    #pragma unroll
    for (int k = 0; k < 8; ++k) {
        #pragma unroll
        for (int m = 0; m < 2; ++m) {
            int row   = (mh * 2 + m) * 16 + lm;
            int chunk = k * 4 + lk;
            short8 hf = *(const short8*)&sH[row * HIDDEN + ((chunk ^ (row & 7)) << 3)];
            #pragma unroll
            for (int j2 = 0; j2 < 2; ++j2)
                acc2[m][j2] = __builtin_amdgcn_mfma_f32_16x16x32_bf16(hf, w2f[k][j2], acc2[m][j2], 0, 0, 0);
        }
    }

    // ---- store out fp32 ----
    #pragma unroll
    for (int m = 0; m < 2; ++m) {
        #pragma unroll
        for (int j2 = 0; j2 < 2; ++j2) {
            #pragma unroll
            for (int r = 0; r < 4; ++r) {
                int grow = base + (mh * 2 + m) * 16 + lk * 4 + r;
                if (grow < N_NODES)
                    out[(size_t)grow * OUT_DIM + (nq * 2 + j2) * 16 + lm] = acc2[m][j2][r];
            }
        }
    }
}

extern "C" void kernel_launch(void* const* d_in, const int* in_sizes, int n_in,
                              void* d_out, int out_size, void* d_ws, size_t ws_size,
                              hipStream_t stream) {
    const float* edge = (const float*)d_in[0];
    const int*   snd  = (const int*)  d_in[1];
    const int*   rcv  = (const int*)  d_in[2];
    const float* node = (const float*)d_in[3];
    const float* glob = (const float*)d_in[4];
    const float* W1   = (const float*)d_in[5];
    const float* b1   = (const float*)d_in[6];
    const float* W2   = (const float*)d_in[7];
    const float* b2   = (const float*)d_in[8];
    float* out = (float*)d_out;

    int* wsi = (int*)d_ws;
    const int wblocks = (K1 * HIDDEN + HIDDEN * OUT_DIM + HIDDEN + 255) / 256;

    if (ws_size >= (size_t)W_TOTAL * 4) {
        unsigned int*   bin      = (unsigned int*)(wsi + W_BIN);
        int*            eids     = wsi + W_EIDS;
        unsigned short* feats_bf = (unsigned short*)(wsi + W_FEATS);
        unsigned short* W1T      = (unsigned short*)(wsi + W_W1T);
        unsigned short* W2T      = (unsigned short*)(wsi + W_W2T);
        float*          b1e      = (float*)(wsi + W_B1E);
        int* off   = wsi + W_OFF;
        int* bcnt  = wsi + W_BCNT;
        int* bbase = wsi + W_BBASE;
        int* bcur  = wsi + W_BCUR;

        hipMemsetAsync(bcnt, 0, NBKT * sizeof(int), stream);
        wcvt_kernel          <<<wblocks, 256, 0, stream>>>(W1, W2, b1, glob, W1T, W2T, b1e);
        bin_count_kernel     <<<NSBLK, 512, 0, stream>>>(rcv, snd, bcnt);
        scan196_kernel       <<<1, 256, 0, stream>>>(bcnt, bbase, bcur, off);
        bin_scatter_ids_kernel<<<NSBLK, 512, 0, stream>>>(rcv, snd, bcur, bin);
        bucket_fill_kernel   <<<NBKT, 1024, 0, stream>>>(bin, bbase, off, eids);
        gather_kernel        <<<(NCNT + 31) / 32, 256, 0, stream>>>(edge, off, eids, feats_bf);
        gemm12_kernel<<<(N_NODES + 63) / 64, 512, 0, stream>>>(
            feats_bf, node, W1T, b1e, W2T, b2, out);
    } else {
        unsigned short* feats_bf = (unsigned short*)(wsi + S_FEATS_W);
        unsigned short* W1T      = (unsigned short*)(wsi + S_W1T_W);
        unsigned short* W2T      = (unsigned short*)(wsi + S_W2T_W);
        float*          b1e      = (float*)(wsi + S_B1E_W);
        int* cnt  = wsi + S_CNT_W;
        int* off  = wsi + S_OFF_W;
        int* pos  = wsi + S_POS_W;
        int* eids = wsi + S_EIDS_W;
        int* bsum = wsi + S_BSUM_W;

        hipMemsetAsync(cnt, 0, NCNT * sizeof(int), stream);
        wcvt_kernel  <<<wblocks, 256, 0, stream>>>(W1, W2, b1, glob, W1T, W2T, b1e);
        const int eblocks = (N_EDGES + 255) / 256;
        hist_kernel  <<<eblocks, 256, 0, stream>>>(snd, rcv, cnt);
        scan1_kernel <<<NSCAN,   256, 0, stream>>>(cnt, off, bsum);
        scan23_kernel<<<NSCAN,   256, 0, stream>>>(off, bsum, pos);
        fill_kernel  <<<eblocks, 256, 0, stream>>>(snd, rcv, pos, eids);
        gather_kernel<<<(NCNT + 31) / 32, 256, 0, stream>>>(edge, off, eids, feats_bf);
        gemm12_kernel<<<(N_NODES + 63) / 64, 512, 0, stream>>>(
            feats_bf, node, W1T, b1e, W2T, b2, out);
    }
}

// Round 14
// 211.948 us; speedup vs baseline: 1.3787x; 1.1476x over previous
//
#include <hip/hip_runtime.h>

#define N_NODES   100000
#define N_EDGES   1600000
#define EDGE_DIM  32
#define NODE_DIM  128
#define K1        192    // rec32 + send32 + node128 (glob folded into b1_eff)
#define HIDDEN    256
#define OUT_DIM   128
#define NCNT      (2 * N_NODES)
#define SCAN_BLK  1024
#define NSCAN     ((NCNT + SCAN_BLK - 1) / SCAN_BLK)   // 196

// ---- two-level counting-sort params ----
#define RSHIFT  10                    // 1024 nodes per range
#define NRANGES 98                    // ceil(100000/1024)
#define NBKT    (2 * NRANGES)         // 196 buckets, dir-major
#define SBLK    4096                  // edges per scatter block
#define NSBLK   ((N_EDGES + SBLK - 1) / SBLK)   // 391

typedef float  f32x4   __attribute__((ext_vector_type(4)));
typedef short  short8  __attribute__((ext_vector_type(8)));
typedef unsigned short ushort8 __attribute__((ext_vector_type(8)));
typedef unsigned short ushort4v __attribute__((ext_vector_type(4)));

// ---- BIG ws layout (4-byte words), ~39.5 MB ----
#define W_BIN    0                           // u32[3.2M] packed (nl<<21|eid)
#define W_EIDS   3200000                     // int[3.2M]
#define W_FEATS  6400000                     // ushort[100000*64] = 3.2M words
#define W_W1T    9600000                     // ushort[256*192]
#define W_W2T    (W_W1T + 24576)             // ushort[128*256]
#define W_B1E    (W_W2T + 16384)             // float[256]
#define W_OFF    (W_B1E + 256)               // int[NCNT+1]
#define W_BCNT   (W_OFF + NCNT + 1)          // int[256]
#define W_BBASE  (W_BCNT + 256)              // int[256] (+sentinel)
#define W_BCUR   (W_BBASE + 256)             // int[256]
#define W_TOTAL  (W_BCUR + 256)

// ---- SMALL ws fallback layout (words), ~28.2 MB (eids path, proven r4/5) ----
#define S_FEATS_W  0
#define S_W1T_W    3200000
#define S_W2T_W    (S_W1T_W + 24576)
#define S_B1E_W    (S_W2T_W + 16384)
#define S_CNT_W    (S_B1E_W + 256)
#define S_OFF_W    (S_CNT_W + NCNT)
#define S_POS_W    (S_OFF_W + NCNT + 1)
#define S_EIDS_W   (S_POS_W + NCNT + 1)
#define S_BSUM_W   (S_EIDS_W + 2 * N_EDGES)

__device__ __forceinline__ unsigned short f2bf(float f) {
    unsigned int u = __float_as_uint(f);
    return (unsigned short)((u + 0x7fffu + ((u >> 16) & 1u)) >> 16);   // RNE
}

// ---------------------------------------------------------------------------
// Weight prep: W1T[n][k] (k<192), W2T[o][k], b1_eff = b1 + glob @ W1[192:224]
// ---------------------------------------------------------------------------
__global__ __launch_bounds__(256) void wcvt_kernel(
    const float* __restrict__ W1, const float* __restrict__ W2,
    const float* __restrict__ b1, const float* __restrict__ glob,
    unsigned short* __restrict__ W1T, unsigned short* __restrict__ W2T,
    float* __restrict__ b1e)
{
    int id = blockIdx.x * 256 + threadIdx.x;
    if (id < K1 * HIDDEN) {
        int n = id / K1, k = id - n * K1;
        W1T[id] = f2bf(W1[(size_t)k * HIDDEN + n]);
    } else if (id < K1 * HIDDEN + HIDDEN * OUT_DIM) {
        int id2 = id - K1 * HIDDEN;
        int o = id2 / HIDDEN, k = id2 - o * HIDDEN;
        W2T[id2] = f2bf(W2[(size_t)k * OUT_DIM + o]);
    } else if (id < K1 * HIDDEN + HIDDEN * OUT_DIM + HIDDEN) {
        int n = id - (K1 * HIDDEN + HIDDEN * OUT_DIM);
        float s = b1[n];
        #pragma unroll
        for (int j = 0; j < 32; ++j)
            s += glob[j] * W1[(size_t)(K1 + j) * HIDDEN + n];
        b1e[n] = s;
    }
}

// ---------------------------------------------------------------------------
// bin_count: 196-bucket histogram, LDS-aggregated
// ---------------------------------------------------------------------------
__global__ __launch_bounds__(512) void bin_count_kernel(
    const int* __restrict__ rcv, const int* __restrict__ snd,
    int* __restrict__ bcnt)
{
    __shared__ int h[NBKT];
    const int tid = threadIdx.x;
    for (int i = tid; i < NBKT; i += 512) h[i] = 0;
    __syncthreads();

    const int base = blockIdx.x * SBLK;
    #pragma unroll
    for (int k = 0; k < SBLK / 512; ++k) {
        int e = base + k * 512 + tid;
        if (e < N_EDGES) {
            atomicAdd(&h[rcv[e] >> RSHIFT], 1);
            atomicAdd(&h[NRANGES + (snd[e] >> RSHIFT)], 1);
        }
    }
    __syncthreads();
    for (int i = tid; i < NBKT; i += 512)
        if (h[i]) atomicAdd(&bcnt[i], h[i]);
}

// ---------------------------------------------------------------------------
// scan196: exclusive scan of bucket counts -> bbase (+sentinel), bcur copy;
// also writes the global CSR sentinel off[NCNT].
// ---------------------------------------------------------------------------
__global__ __launch_bounds__(256) void scan196_kernel(
    const int* __restrict__ bcnt, int* __restrict__ bbase, int* __restrict__ bcur,
    int* __restrict__ off)
{
    __shared__ int ts[256];
    const int t = threadIdx.x;
    int v = (t < NBKT) ? bcnt[t] : 0;
    ts[t] = v;
    __syncthreads();
    for (int d = 1; d < 256; d <<= 1) {
        int x = (t >= d) ? ts[t - d] : 0;
        __syncthreads();
        ts[t] += x;
        __syncthreads();
    }
    if (t < NBKT) { int ex = ts[t] - v; bbase[t] = ex; bcur[t] = ex; }
    if (t == 255) { bbase[NBKT] = ts[255]; off[NCNT] = 2 * N_EDGES; }
}

// ---------------------------------------------------------------------------
// bin_scatter_ids: block owns 4096 edges; packs (nl<<21)|eid and scatters
// into bucket-chunked regions (one global cursor claim per block-bucket).
// ---------------------------------------------------------------------------
__global__ __launch_bounds__(512) void bin_scatter_ids_kernel(
    const int* __restrict__ rcv, const int* __restrict__ snd,
    int*         __restrict__ bcur,
    unsigned int* __restrict__ bin)
{
    __shared__ int cntA[NBKT];
    __shared__ int baseS[NBKT];
    __shared__ int cntC[NBKT];

    const int tid  = threadIdx.x;
    const int base = blockIdx.x * SBLK;

    for (int i = tid; i < NBKT; i += 512) { cntA[i] = 0; cntC[i] = 0; }
    __syncthreads();

    int rk[SBLK / 512], sk[SBLK / 512];
    #pragma unroll
    for (int k = 0; k < SBLK / 512; ++k) {
        int e = base + k * 512 + tid;
        if (e < N_EDGES) {
            rk[k] = rcv[e]; sk[k] = snd[e];
            atomicAdd(&cntA[rk[k] >> RSHIFT], 1);
            atomicAdd(&cntA[NRANGES + (sk[k] >> RSHIFT)], 1);
        } else rk[k] = -1;
    }
    __syncthreads();

    for (int i = tid; i < NBKT; i += 512)
        baseS[i] = cntA[i] ? atomicAdd(&bcur[i], cntA[i]) : 0;
    __syncthreads();

    #pragma unroll
    for (int k = 0; k < SBLK / 512; ++k) {
        if (rk[k] < 0) continue;
        int e  = base + k * 512 + tid;
        int b0 = rk[k] >> RSHIFT;
        int b1 = NRANGES + (sk[k] >> RSHIFT);
        int s0 = baseS[b0] + atomicAdd(&cntC[b0], 1);
        int s1 = baseS[b1] + atomicAdd(&cntC[b1], 1);
        bin[s0] = ((unsigned)(rk[k] & ((1 << RSHIFT) - 1)) << 21) | (unsigned)e;
        bin[s1] = ((unsigned)(sk[k] & ((1 << RSHIFT) - 1)) << 21) | (unsigned)e;
    }
}

// ---------------------------------------------------------------------------
// bucket_fill: one block per bucket. LDS hist(1024) -> scan -> writes global
// CSR off[] AND scatters eids into the bucket's own L2-local span.
// ---------------------------------------------------------------------------
__global__ __launch_bounds__(1024) void bucket_fill_kernel(
    const unsigned int* __restrict__ bin,
    const int* __restrict__ bbase,
    int* __restrict__ off,
    int* __restrict__ eids)
{
    __shared__ int hist[1024];
    __shared__ int ts[1024];
    __shared__ int cur[1024];

    const int tid = threadIdx.x;
    const int b   = blockIdx.x;
    const int dir = (b >= NRANGES) ? 1 : 0;
    const int r   = dir ? (b - NRANGES) : b;
    const int lo  = r << RSHIFT;
    const int s0  = bbase[b], s1 = bbase[b + 1];

    hist[tid] = 0;
    __syncthreads();

    for (int i = s0 + tid; i < s1; i += 1024)
        atomicAdd(&hist[bin[i] >> 21], 1);
    __syncthreads();

    int v = hist[tid];
    ts[tid] = v;
    __syncthreads();
    for (int d = 1; d < 1024; d <<= 1) {
        int x = (tid >= d) ? ts[tid - d] : 0;
        __syncthreads();
        ts[tid] += x;
        __syncthreads();
    }
    int slot0 = s0 + ts[tid] - v;
    cur[tid] = slot0;

    const int rangeN = min(1024, N_NODES - lo);
    if (tid < rangeN) off[dir * N_NODES + lo + tid] = slot0;
    __syncthreads();

    for (int i = s0 + tid; i < s1; i += 1024) {
        unsigned int u = bin[i];
        int nl = u >> 21;
        int s = atomicAdd(&cur[nl], 1);
        eids[s] = (int)(u & 0x1FFFFFu);
    }
}

// ---------------------------------------------------------------------------
// gather: 8 lanes per (node,dir) segment sum fp32 edge rows via eids.
// Unrolled x4: gather is outstanding-miss-bound (random 128B rows).
// ---------------------------------------------------------------------------
__global__ __launch_bounds__(256) void gather_kernel(
    const float* __restrict__ edge,
    const int*   __restrict__ off,
    const int*   __restrict__ eids,
    unsigned short* __restrict__ feats_bf)
{
    int seg = blockIdx.x * 32 + (threadIdx.x >> 3);
    if (seg >= NCNT) return;
    const int sub = threadIdx.x & 7;
    int s = off[seg], e = off[seg + 1];

    float4 a0 = make_float4(0.f, 0.f, 0.f, 0.f);
    float4 a1 = make_float4(0.f, 0.f, 0.f, 0.f);
    float4 a2 = make_float4(0.f, 0.f, 0.f, 0.f);
    float4 a3 = make_float4(0.f, 0.f, 0.f, 0.f);
    int i = s;
    for (; i + 4 <= e; i += 4) {
        int e0 = eids[i], e1 = eids[i + 1], e2 = eids[i + 2], e3 = eids[i + 3];
        float4 v0 = *(const float4*)&edge[(size_t)e0 * EDGE_DIM + sub * 4];
        float4 v1 = *(const float4*)&edge[(size_t)e1 * EDGE_DIM + sub * 4];
        float4 v2 = *(const float4*)&edge[(size_t)e2 * EDGE_DIM + sub * 4];
        float4 v3 = *(const float4*)&edge[(size_t)e3 * EDGE_DIM + sub * 4];
        a0.x += v0.x; a0.y += v0.y; a0.z += v0.z; a0.w += v0.w;
        a1.x += v1.x; a1.y += v1.y; a1.z += v1.z; a1.w += v1.w;
        a2.x += v2.x; a2.y += v2.y; a2.z += v2.z; a2.w += v2.w;
        a3.x += v3.x; a3.y += v3.y; a3.z += v3.z; a3.w += v3.w;
    }
    for (; i < e; ++i) {
        float4 v = *(const float4*)&edge[(size_t)eids[i] * EDGE_DIM + sub * 4];
        a0.x += v.x; a0.y += v.y; a0.z += v.z; a0.w += v.w;
    }
    a0.x += a1.x + a2.x + a3.x;
    a0.y += a1.y + a2.y + a3.y;
    a0.z += a1.z + a2.z + a3.z;
    a0.w += a1.w + a2.w + a3.w;

    int nodeI = (seg < N_NODES) ? seg : (seg - N_NODES);
    int colB  = (seg < N_NODES) ? 0 : 32;
    ushort4v r;
    r.x = f2bf(a0.x); r.y = f2bf(a0.y); r.z = f2bf(a0.z); r.w = f2bf(a0.w);
    *(ushort4v*)&feats_bf[(size_t)nodeI * 64 + colB + sub * 4] = r;
}

// ---------------------------------------------------------------------------
// Small-ws fallback kernels (proven r4/5)
// ---------------------------------------------------------------------------
__global__ __launch_bounds__(256) void hist_kernel(
    const int* __restrict__ snd, const int* __restrict__ rcv, int* __restrict__ cnt)
{
    int e = blockIdx.x * 256 + threadIdx.x;
    if (e >= N_EDGES) return;
    atomicAdd(&cnt[rcv[e]], 1);
    atomicAdd(&cnt[N_NODES + snd[e]], 1);
}

__global__ __launch_bounds__(256) void scan1_kernel(
    const int* __restrict__ cnt, int* __restrict__ off, int* __restrict__ bsum)
{
    __shared__ int ts[256];
    const int t = threadIdx.x;
    const int base = blockIdx.x * SCAN_BLK + t * 4;
    int v[4], s = 0;
    #pragma unroll
    for (int j = 0; j < 4; ++j) {
        int idx = base + j;
        v[j] = (idx < NCNT) ? cnt[idx] : 0;
        s += v[j];
    }
    ts[t] = s;
    __syncthreads();
    for (int d = 1; d < 256; d <<= 1) {
        int x = (t >= d) ? ts[t - d] : 0;
        __syncthreads();
        ts[t] += x;
        __syncthreads();
    }
    int run = ts[t] - s;
    #pragma unroll
    for (int j = 0; j < 4; ++j) {
        int idx = base + j;
        if (idx < NCNT) off[idx] = run;
        run += v[j];
    }
    if (t == 255) bsum[blockIdx.x] = ts[255];
}

__global__ __launch_bounds__(256) void scan23_kernel(
    int* __restrict__ off, const int* __restrict__ bsum, int* __restrict__ pos)
{
    __shared__ int ts[256];
    __shared__ int sboff;
    const int t = threadIdx.x;
    int v = (t < NSCAN) ? bsum[t] : 0;
    ts[t] = v;
    __syncthreads();
    for (int d = 1; d < 256; d <<= 1) {
        int x = (t >= d) ? ts[t - d] : 0;
        __syncthreads();
        ts[t] += x;
        __syncthreads();
    }
    if (t == (int)blockIdx.x) sboff = ts[t] - v;
    __syncthreads();
    const int bo = sboff;
    const int base = blockIdx.x * SCAN_BLK + t * 4;
    #pragma unroll
    for (int j = 0; j < 4; ++j) {
        int idx = base + j;
        if (idx < NCNT) {
            int o = off[idx] + bo;
            off[idx] = o;
            pos[idx] = o;
        }
    }
    if (blockIdx.x == 0 && t == 0) off[NCNT] = 2 * N_EDGES;
}

__global__ __launch_bounds__(256) void fill_kernel(
    const int* __restrict__ snd, const int* __restrict__ rcv,
    int* __restrict__ pos, int* __restrict__ eids)
{
    int e = blockIdx.x * 256 + threadIdx.x;
    if (e >= N_EDGES) return;
    int p = atomicAdd(&pos[rcv[e]], 1);
    eids[p] = e;
    int q = atomicAdd(&pos[N_NODES + snd[e]], 1);
    eids[q] = e;
}

// ---------------------------------------------------------------------------
// Fused GEMM1+GEMM2: 64 nodes/block, 512 threads (8 waves). r11-proven:
// wave w owns GEMM1 h-cols [32w,32w+32) (W1 frags in regs), GEMM2 out-cols
// [16w,16w+16) (W2 frags in regs). A and h in XOR-swizzled LDS (bf16).
// ---------------------------------------------------------------------------
__global__ __launch_bounds__(512) void gemm12_kernel(
    const unsigned short* __restrict__ feats_bf,
    const float* __restrict__ node,
    const unsigned short* __restrict__ W1T,
    const float* __restrict__ b1e,
    const unsigned short* __restrict__ W2T,
    const float* __restrict__ b2,
    float*       __restrict__ out)
{
    __shared__ unsigned short sA[64 * K1];       // 24 KB
    __shared__ unsigned short sH[64 * HIDDEN];   // 32 KB

    const int tid  = threadIdx.x;
    const int base = blockIdx.x * 64;

    for (int idx = tid; idx < 64 * 24; idx += 512) {
        int row = idx / 24;
        int c   = idx - row * 24;
        int g   = base + row; if (g >= N_NODES) g = N_NODES - 1;
        ushort8 r;
        if (c < 8) {
            r = *(const ushort8*)&feats_bf[(size_t)g * 64 + c * 8];
        } else {
            const float* np = &node[(size_t)g * NODE_DIM + (c - 8) * 8];
            float4 v0 = *(const float4*)np;
            float4 v1 = *(const float4*)(np + 4);
            r[0] = f2bf(v0.x); r[1] = f2bf(v0.y); r[2] = f2bf(v0.z); r[3] = f2bf(v0.w);
            r[4] = f2bf(v1.x); r[5] = f2bf(v1.y); r[6] = f2bf(v1.z); r[7] = f2bf(v1.w);
        }
        *(ushort8*)&sA[row * K1 + ((c ^ (row & 7)) << 3)] = r;
    }
    __syncthreads();

    const int wave = tid >> 6;
    const int lane = tid & 63;
    const int lm   = lane & 15;
    const int lk   = lane >> 4;

    short8 w1f[2][6];
    #pragma unroll
    for (int j = 0; j < 2; ++j) {
        int nt = 2 * wave + j;
        #pragma unroll
        for (int k = 0; k < 6; ++k)
            w1f[j][k] = *(const short8*)&W1T[(size_t)(nt * 16 + lm) * K1 + k * 32 + lk * 8];
    }

    f32x4 acc1[4][2];
    {
        float bv0 = b1e[(2 * wave) * 16 + lm];
        float bv1 = b1e[(2 * wave + 1) * 16 + lm];
        #pragma unroll
        for (int m = 0; m < 4; ++m) {
            acc1[m][0] = (f32x4){bv0, bv0, bv0, bv0};
            acc1[m][1] = (f32x4){bv1, bv1, bv1, bv1};
        }
    }

    #pragma unroll
    for (int k = 0; k < 6; ++k) {
        #pragma unroll
        for (int m = 0; m < 4; ++m) {
            int row   = m * 16 + lm;
            int chunk = k * 4 + lk;
            short8 af = *(const short8*)&sA[row * K1 + ((chunk ^ (row & 7)) << 3)];
            acc1[m][0] = __builtin_amdgcn_mfma_f32_16x16x32_bf16(af, w1f[0][k], acc1[m][0], 0, 0, 0);
            acc1[m][1] = __builtin_amdgcn_mfma_f32_16x16x32_bf16(af, w1f[1][k], acc1[m][1], 0, 0, 0);
        }
    }

    #pragma unroll
    for (int m = 0; m < 4; ++m) {
        #pragma unroll
        for (int j = 0; j < 2; ++j) {
            int col   = (2 * wave + j) * 16 + lm;
            int chunk = col >> 3;
            int cin   = col & 7;
            #pragma unroll
            for (int r = 0; r < 4; ++r) {
                int rowl = m * 16 + lk * 4 + r;
                float v = fmaxf(acc1[m][j][r], 0.0f);
                sH[rowl * HIDDEN + ((chunk ^ (rowl & 7)) << 3) + cin] = f2bf(v);
            }
        }
    }

    short8 w2f[8];
    #pragma unroll
    for (int k = 0; k < 8; ++k)
        w2f[k] = *(const short8*)&W2T[(size_t)(wave * 16 + lm) * HIDDEN + k * 32 + lk * 8];

    f32x4 acc2[4];
    {
        float bv = b2[wave * 16 + lm];
        #pragma unroll
        for (int m = 0; m < 4; ++m) acc2[m] = (f32x4){bv, bv, bv, bv};
    }
    __syncthreads();

    #pragma unroll
    for (int k = 0; k < 8; ++k) {
        #pragma unroll
        for (int m = 0; m < 4; ++m) {
            int row   = m * 16 + lm;
            int chunk = k * 4 + lk;
            short8 hf = *(const short8*)&sH[row * HIDDEN + ((chunk ^ (row & 7)) << 3)];
            acc2[m] = __builtin_amdgcn_mfma_f32_16x16x32_bf16(hf, w2f[k], acc2[m], 0, 0, 0);
        }
    }

    #pragma unroll
    for (int m = 0; m < 4; ++m) {
        #pragma unroll
        for (int r = 0; r < 4; ++r) {
            int grow = base + m * 16 + lk * 4 + r;
            if (grow < N_NODES)
                out[(size_t)grow * OUT_DIM + wave * 16 + lm] = acc2[m][r];
        }
    }
}

extern "C" void kernel_launch(void* const* d_in, const int* in_sizes, int n_in,
                              void* d_out, int out_size, void* d_ws, size_t ws_size,
                              hipStream_t stream) {
    const float* edge = (const float*)d_in[0];
    const int*   snd  = (const int*)  d_in[1];
    const int*   rcv  = (const int*)  d_in[2];
    const float* node = (const float*)d_in[3];
    const float* glob = (const float*)d_in[4];
    const float* W1   = (const float*)d_in[5];
    const float* b1   = (const float*)d_in[6];
    const float* W2   = (const float*)d_in[7];
    const float* b2   = (const float*)d_in[8];
    float* out = (float*)d_out;

    int* wsi = (int*)d_ws;
    const int wblocks = (K1 * HIDDEN + HIDDEN * OUT_DIM + HIDDEN + 255) / 256;

    if (ws_size >= (size_t)W_TOTAL * 4) {
        unsigned int*   bin      = (unsigned int*)(wsi + W_BIN);
        int*            eids     = wsi + W_EIDS;
        unsigned short* feats_bf = (unsigned short*)(wsi + W_FEATS);
        unsigned short* W1T      = (unsigned short*)(wsi + W_W1T);
        unsigned short* W2T      = (unsigned short*)(wsi + W_W2T);
        float*          b1e      = (float*)(wsi + W_B1E);
        int* off   = wsi + W_OFF;
        int* bcnt  = wsi + W_BCNT;
        int* bbase = wsi + W_BBASE;
        int* bcur  = wsi + W_BCUR;

        hipMemsetAsync(bcnt, 0, NBKT * sizeof(int), stream);
        wcvt_kernel          <<<wblocks, 256, 0, stream>>>(W1, W2, b1, glob, W1T, W2T, b1e);
        bin_count_kernel     <<<NSBLK, 512, 0, stream>>>(rcv, snd, bcnt);
        scan196_kernel       <<<1, 256, 0, stream>>>(bcnt, bbase, bcur, off);
        bin_scatter_ids_kernel<<<NSBLK, 512, 0, stream>>>(rcv, snd, bcur, bin);
        bucket_fill_kernel   <<<NBKT, 1024, 0, stream>>>(bin, bbase, off, eids);
        gather_kernel        <<<(NCNT + 31) / 32, 256, 0, stream>>>(edge, off, eids, feats_bf);
        gemm12_kernel<<<(N_NODES + 63) / 64, 512, 0, stream>>>(
            feats_bf, node, W1T, b1e, W2T, b2, out);
    } else {
        unsigned short* feats_bf = (unsigned short*)(wsi + S_FEATS_W);
        unsigned short* W1T      = (unsigned short*)(wsi + S_W1T_W);
        unsigned short* W2T      = (unsigned short*)(wsi + S_W2T_W);
        float*          b1e      = (float*)(wsi + S_B1E_W);
        int* cnt  = wsi + S_CNT_W;
        int* off  = wsi + S_OFF_W;
        int* pos  = wsi + S_POS_W;
        int* eids = wsi + S_EIDS_W;
        int* bsum = wsi + S_BSUM_W;

        hipMemsetAsync(cnt, 0, NCNT * sizeof(int), stream);
        wcvt_kernel  <<<wblocks, 256, 0, stream>>>(W1, W2, b1, glob, W1T, W2T, b1e);
        const int eblocks = (N_EDGES + 255) / 256;
        hist_kernel  <<<eblocks, 256, 0, stream>>>(snd, rcv, cnt);
        scan1_kernel <<<NSCAN,   256, 0, stream>>>(cnt, off, bsum);
        scan23_kernel<<<NSCAN,   256, 0, stream>>>(off, bsum, pos);
        fill_kernel  <<<eblocks, 256, 0, stream>>>(snd, rcv, pos, eids);
        gather_kernel<<<(NCNT + 31) / 32, 256, 0, stream>>>(edge, off, eids, feats_bf);
        gemm12_kernel<<<(N_NODES + 63) / 64, 512, 0, stream>>>(
            feats_bf, node, W1T, b1e, W2T, b2, out);
    }
}